// Round 8
// baseline (1466.294 us; speedup 1.0000x reference)
//
#include <hip/hip_runtime.h>
#include <hip/hip_bf16.h>
#include <hip/hip_fp16.h>
#include <stdint.h>

#define T_STEPS 256
#define BATCH 512
#define GROUPS 32         // 16 samples each
#define CHUNKS 8          // N-split: 32 j-dims (128 gate-cols) per chunk

typedef _Float16 f16x8 __attribute__((ext_vector_type(8)));
typedef _Float16 h2_t  __attribute__((ext_vector_type(2)));
typedef float    f32x4 __attribute__((ext_vector_type(4)));

__device__ __forceinline__ float fdot2(uint32_t w, uint32_t c, float acc) {
#if __has_builtin(__builtin_amdgcn_fdot2)
    h2_t a, b;
    __builtin_memcpy(&a, &w, 4);
    __builtin_memcpy(&b, &c, 4);
    return __builtin_amdgcn_fdot2(a, b, acc, false);
#else
    union { uint32_t u; _Float16 h[2]; } A, B;
    A.u = w; B.u = c;
    return acc + (float)A.h[0]*(float)B.h[0] + (float)A.h[1]*(float)B.h[1];
#endif
}

__device__ __forceinline__ float sigmoidf_(float x) {
    return 1.f / (1.f + __expf(-x));
}
__device__ __forceinline__ float tanhf_(float x) {
    float ax = fabsf(x);
    float e = __expf(-2.f * ax);
    float r = (1.f - e) / (1.f + e);
    return copysignf(r, x);
}

// ---------------- prep: concat QCNN weights ----------------
__global__ void concat_qw(const float* __restrict__ fm_w, const float* __restrict__ fm_b,
                          const float* __restrict__ c1_w, const float* __restrict__ c1_b,
                          const float* __restrict__ p1_w, const float* __restrict__ p1_b,
                          const float* __restrict__ c2_w, const float* __restrict__ c2_b,
                          const float* __restrict__ p2_w, const float* __restrict__ p2_b,
                          const float* __restrict__ c3_w, const float* __restrict__ c3_b,
                          float* __restrict__ qw) {
    for (int k = threadIdx.x; k < 780; k += 256) {
        float v;
        if      (k < 128) v = fm_w[k];
        else if (k < 144) v = fm_b[k-128];
        else if (k < 400) v = c1_w[k-144];
        else if (k < 416) v = c1_b[k-400];
        else if (k < 608) v = p1_w[k-416];
        else if (k < 620) v = p1_b[k-608];
        else if (k < 716) v = c2_w[k-620];
        else if (k < 724) v = c2_b[k-716];
        else if (k < 756) v = p2_w[k-724];
        else if (k < 760) v = p2_b[k-756];
        else if (k < 776) v = c3_w[k-760];
        else              v = c3_b[k-776];
        qw[k] = v;
    }
}

// ---------------- prep: B-fragments, chunked layout ----------------
// bf[((c*8 + n)*8 + q)*64 + l]: chunk c owns j in [c*32,c*32+32); tile n:
// gate g = n>>1, j = c*32 + (n&1)*16 + (l&15); k = q*32 + (l>>4)*8 + e.
// (k-order errors cancel: A read with same mapping.)
__global__ void pack_bfrag2(const float* __restrict__ f_w, const float* __restrict__ i_w,
                            const float* __restrict__ u_w, const float* __restrict__ o_w,
                            uint4* __restrict__ bf) {
    int idx = blockIdx.x * 256 + threadIdx.x;      // 0..32767
    int l = idx & 63, q = (idx >> 6) & 7, n = (idx >> 9) & 7, c = idx >> 12;
    int j = c * 32 + (n & 1) * 16 + (l & 15);
    int g = n >> 1;
    const float* W = (g == 0) ? f_w : (g == 1) ? i_w : (g == 2) ? u_w : o_w;
    union { uint4 u; _Float16 h[8]; } P;
#pragma unroll
    for (int e = 0; e < 8; ++e) {
        int k = q * 32 + ((l >> 4) * 8) + e;
        P.h[e] = (_Float16)W[j * 260 + 4 + k];
    }
    bf[idx] = P.u;
}

// ---------------- prep: x-part weights xwG[g][k][j] f16 ----------------
__global__ void pack_xw(const float* __restrict__ f_w, const float* __restrict__ i_w,
                        const float* __restrict__ u_w, const float* __restrict__ o_w,
                        _Float16* __restrict__ xwG) {
    int t = blockIdx.x * 256 + threadIdx.x;        // 0..4095
    int g = t >> 10, k = (t >> 8) & 3, j = t & 255;
    const float* W = (g == 0) ? f_w : (g == 1) ? i_w : (g == 2) ? u_w : o_w;
    xwG[t] = (_Float16)W[j * 260 + k];
}

// ---------------- QCNN feature extractor ----------------
__global__ void qcnn_kernel(const float* __restrict__ in, const float* __restrict__ qw,
                            _Float16* __restrict__ feats) {
    int r = blockIdx.x * 256 + threadIdx.x;   // 0..131071
    const float* x = in + (size_t)r * 8;
    float v0[8];
#pragma unroll
    for (int i = 0; i < 8; ++i) v0[i] = x[i];
    float v1[16];
#pragma unroll
    for (int o = 0; o < 16; ++o) {
        float s = qw[128 + o];
#pragma unroll
        for (int i = 0; i < 8; ++i) s += qw[o*8 + i] * v0[i];
        v1[o] = tanhf_(s);
    }
    float v2[16];
#pragma unroll
    for (int o = 0; o < 16; ++o) {
        float s = qw[400 + o];
#pragma unroll
        for (int i = 0; i < 16; ++i) s += qw[144 + o*16 + i] * v1[i];
        v2[o] = tanhf_(s);
    }
    float v3[12];
#pragma unroll
    for (int o = 0; o < 12; ++o) {
        float s = qw[608 + o];
#pragma unroll
        for (int i = 0; i < 16; ++i) s += qw[416 + o*16 + i] * v2[i];
        v3[o] = tanhf_(s);
    }
    float v4[8];
#pragma unroll
    for (int o = 0; o < 8; ++o) {
        float s = qw[716 + o];
#pragma unroll
        for (int i = 0; i < 12; ++i) s += qw[620 + o*12 + i] * v3[i];
        v4[o] = tanhf_(s);
    }
    float v5[4];
#pragma unroll
    for (int o = 0; o < 4; ++o) {
        float s = qw[756 + o];
#pragma unroll
        for (int i = 0; i < 8; ++i) s += qw[724 + o*8 + i] * v4[i];
        v5[o] = tanhf_(s);
    }
    union { uint32_t u[2]; _Float16 h[4]; } P;
#pragma unroll
    for (int o = 0; o < 4; ++o) {
        float s = qw[776 + o];
#pragma unroll
        for (int i = 0; i < 4; ++i) s += qw[760 + o*4 + i] * v5[i];
        P.h[o] = (_Float16)tanhf_(s);
    }
    *reinterpret_cast<uint2*>(feats + (size_t)r * 4) = make_uint2(P.u[0], P.u[1]);
}

// ---------------- persistent M=16 N-split LSTM ----------------
// 256 blocks (= CU count -> all co-resident), 256 threads (4 waves).
// Block: group g = blockIdx&31 (samples g*16..+15), chunk c = blockIdx>>5
// (j-dims c*32..+31, i.e. gate-cols [4 gates][32 j]). Stride-32 grouping puts a
// group's 8 chunks on one XCD under the typical round-robin mapping (perf only).
// Per step: gather h(t) [16x256 f16, agent-scope loads from hx] -> MFMA
// A[16x256].B[256x128] = 64 MFMA (16/wave, B fully VGPR-resident: 16 frags) ->
// epilogue (512 (j,s) pairs, 2/thread, c-state in regs) -> publish h(t+1)
// chunk + release flag. Double-buffered hx + monotonic flags: flag tau+1
// implies that block finished READING h(tau), so overwriting h(tau+2) into the
// same parity is safe. Flags+hx[0] zeroed each launch by stream-ordered memset.
__global__ __launch_bounds__(256, 1)
void lstm_kernel(const uint4* __restrict__ bfrags2, const _Float16* __restrict__ xwG,
                 const _Float16* __restrict__ feats,
                 const float* __restrict__ f_b, const float* __restrict__ i_b,
                 const float* __restrict__ u_b, const float* __restrict__ o_b,
                 const float* __restrict__ head_w, const float* __restrict__ head_bp,
                 uint32_t* __restrict__ flags, uint32_t* __restrict__ hx,
                 float* __restrict__ out) {
    __shared__ _Float16 hL[16][264];        // gathered h(t), +8 pad (2-way banks)
    __shared__ float    stripL[4][32][20];  // [gate][j][sample] C results, +4 pad
    __shared__ _Float16 hpubL[16][32];      // own h(t+1) chunk staging
    __shared__ float    hwL[256];           // head weights

    const int tid = threadIdx.x;
    const int w   = tid >> 6;               // wave = gate
    const int l   = tid & 63;
    const int g   = blockIdx.x & 31;        // group
    const int c   = blockIdx.x >> 5;        // chunk

    // ---- step-invariant preloads ----
    f16x8 Brg[2][8];                        // B frags: n = 2w+nn, q = 0..7
#pragma unroll
    for (int nn = 0; nn < 2; ++nn)
#pragma unroll
        for (int q = 0; q < 8; ++q)
            Brg[nn][q] = *reinterpret_cast<const f16x8*>(
                bfrags2 + (((c * 8 + (2 * w + nn)) * 8) + q) * 64 + l);

    const int jj = tid & 31;                // epilogue j within chunk
    const int se = tid >> 5;                // epilogue samples se, se+8
    const int jglob = c * 32 + jj;
    float bias_[4] = { f_b[jglob], i_b[jglob], u_b[jglob], o_b[jglob] };
    uint32_t xw01[4], xw23[4];
#pragma unroll
    for (int gg = 0; gg < 4; ++gg) {
        union { uint32_t u; _Float16 h[2]; } P;
        P.h[0] = xwG[gg*1024 +       jglob]; P.h[1] = xwG[gg*1024 + 256 + jglob];
        xw01[gg] = P.u;
        P.h[0] = xwG[gg*1024 + 512 + jglob]; P.h[1] = xwG[gg*1024 + 768 + jglob];
        xw23[gg] = P.u;
    }
    const float hb = head_bp[0];
    hwL[tid] = head_w[tid];

    uint32_t* const myflags = flags + g * 8;
    float cs0 = 0.f, cs1 = 0.f;             // c-state for (jglob, se) and (jglob, se+8)

#pragma unroll 1
    for (int tau = 0; tau <= T_STEPS; ++tau) {
        const bool last = (tau == T_STEPS);
        if (last && c != 0) break;          // only chunk 0 needs the final gather (head)

        // ---- spin until all 8 chunks published h(tau) ----
        if (tid < 8) {
            while (__hip_atomic_load(&myflags[tid], __ATOMIC_ACQUIRE,
                                     __HIP_MEMORY_SCOPE_AGENT) < (uint32_t)tau)
                __builtin_amdgcn_s_sleep(1);
        }
        __syncthreads();

        // x_t loads (consumed in epilogue; covered by gather+MFMA latency)
        uint2 xr0 = make_uint2(0u, 0u), xr1 = xr0;
        if (!last) {
            xr0 = *reinterpret_cast<const uint2*>(feats + ((size_t)tau * BATCH + g * 16 + se    ) * 4);
            xr1 = *reinterpret_cast<const uint2*>(feats + ((size_t)tau * BATCH + g * 16 + se + 8) * 4);
        }

        // ---- gather h(tau): 2048 u32 agent loads -> hL ----
        {
            const uint32_t* hsrc = hx + ((size_t)(tau & 1)) * (GROUPS*16*128) + g * (16*128);
            uint32_t v[8];
#pragma unroll
            for (int i = 0; i < 8; ++i) {
                int idx = tid + i * 256, s = idx >> 7, dp = idx & 127;
                v[i] = __hip_atomic_load(hsrc + s * 128 + dp, __ATOMIC_RELAXED,
                                         __HIP_MEMORY_SCOPE_AGENT);
            }
#pragma unroll
            for (int i = 0; i < 8; ++i) {
                int idx = tid + i * 256, s = idx >> 7, dp = idx & 127;
                *reinterpret_cast<uint32_t*>(&hL[s][dp * 2]) = v[i];
            }
        }
        __syncthreads();

        // ---- head (chunk 0 only, deterministic): out[tau-1] from h(tau) ----
        if (c == 0 && tau >= 1) {
            const int sh = tid >> 4, d0 = (tid & 15) * 16;
            float p = 0.f;
#pragma unroll
            for (int d = 0; d < 16; ++d) p += (float)hL[sh][d0 + d] * hwL[d0 + d];
            p += __shfl_down(p, 8); p += __shfl_down(p, 4);
            p += __shfl_down(p, 2); p += __shfl_down(p, 1);
            if ((tid & 15) == 0)
                out[(size_t)(tau - 1) * BATCH + g * 16 + sh] = p + hb;
        }
        if (last) break;

        // ---- MFMA: C[16 x 128] = h . W^T  (A row = l&15, k = (l>>4)*8+e) ----
        f16x8 A_[8];
#pragma unroll
        for (int q = 0; q < 8; ++q)
            A_[q] = *reinterpret_cast<const f16x8*>(&hL[l & 15][q * 32 + (l >> 4) * 8]);
        f32x4 C0 = {0.f,0.f,0.f,0.f}, C1 = {0.f,0.f,0.f,0.f};
#pragma unroll
        for (int q = 0; q < 8; ++q) {
            C0 = __builtin_amdgcn_mfma_f32_16x16x32_f16(A_[q], Brg[0][q], C0, 0, 0, 0);
            C1 = __builtin_amdgcn_mfma_f32_16x16x32_f16(A_[q], Brg[1][q], C1, 0, 0, 0);
        }
        // C layout (HW-verified m89): col = l&15, row = (l>>4)*4 + reg
        *reinterpret_cast<f32x4*>(&stripL[w][ 0 + (l & 15)][(l >> 4) * 4]) = C0;
        *reinterpret_cast<f32x4*>(&stripL[w][16 + (l & 15)][(l >> 4) * 4]) = C1;
        __syncthreads();

        // ---- epilogue: thread -> (jglob, se) and (jglob, se+8) ----
        float pre0[4], pre1[4];
#pragma unroll
        for (int gg = 0; gg < 4; ++gg) {
            const float a = stripL[gg][jj][se];
            const float b = stripL[gg][jj][se + 8];
            pre0[gg] = fdot2(xw01[gg], xr0.x, fdot2(xw23[gg], xr0.y, a + bias_[gg]));
            pre1[gg] = fdot2(xw01[gg], xr1.x, fdot2(xw23[gg], xr1.y, b + bias_[gg]));
        }
        const float fg0 = sigmoidf_(pre0[0]), fg1 = sigmoidf_(pre1[0]);
        const float ig0 = sigmoidf_(pre0[1]), ig1 = sigmoidf_(pre1[1]);
        const float ug0 = tanhf_(pre0[2]),    ug1 = tanhf_(pre1[2]);
        const float og0 = sigmoidf_(pre0[3]), og1 = sigmoidf_(pre1[3]);
        cs0 = fg0 * cs0 + ig0 * ug0;
        cs1 = fg1 * cs1 + ig1 * ug1;
        hpubL[se    ][jj] = (_Float16)(og0 * tanhf_(cs0));
        hpubL[se + 8][jj] = (_Float16)(og1 * tanhf_(cs1));
        __syncthreads();

        // ---- publish h(tau+1) chunk: 256 u32 agent stores + release flag ----
        {
            uint32_t* hdst = hx + ((size_t)((tau + 1) & 1)) * (GROUPS*16*128) + g * (16*128);
            const int s = tid >> 4, dp0 = tid & 15;
            const uint32_t v = reinterpret_cast<const uint32_t*>(&hpubL[0][0])[tid];
            __hip_atomic_store(hdst + s * 128 + c * 16 + dp0, v, __ATOMIC_RELAXED,
                               __HIP_MEMORY_SCOPE_AGENT);
            asm volatile("s_waitcnt vmcnt(0)" ::: "memory");
        }
        __syncthreads();
        if (tid == 0)
            __hip_atomic_store(&myflags[c], (uint32_t)(tau + 1), __ATOMIC_RELEASE,
                               __HIP_MEMORY_SCOPE_AGENT);
    }
}

extern "C" void kernel_launch(void* const* d_in, const int* in_sizes, int n_in,
                              void* d_out, int out_size, void* d_ws, size_t ws_size,
                              hipStream_t stream) {
    const float* inputs = (const float*)d_in[0];
    const float* fm_w = (const float*)d_in[1];  const float* fm_b = (const float*)d_in[2];
    const float* c1_w = (const float*)d_in[3];  const float* c1_b = (const float*)d_in[4];
    const float* p1_w = (const float*)d_in[5];  const float* p1_b = (const float*)d_in[6];
    const float* c2_w = (const float*)d_in[7];  const float* c2_b = (const float*)d_in[8];
    const float* p2_w = (const float*)d_in[9];  const float* p2_b = (const float*)d_in[10];
    const float* c3_w = (const float*)d_in[11]; const float* c3_b = (const float*)d_in[12];
    const float* f_w  = (const float*)d_in[13]; const float* f_b  = (const float*)d_in[14];
    const float* i_w  = (const float*)d_in[15]; const float* i_b  = (const float*)d_in[16];
    const float* u_w  = (const float*)d_in[17]; const float* u_b  = (const float*)d_in[18];
    const float* o_w  = (const float*)d_in[19]; const float* o_b  = (const float*)d_in[20];
    const float* head_w = (const float*)d_in[21];
    const float* head_b = (const float*)d_in[22];

    // workspace layout (16B aligned)
    uint32_t*  flags   = (uint32_t*)d_ws;                             //    1024 B
    uint32_t*  hx      = (uint32_t*)((char*)d_ws + 1024);             //  524288 B [2][32][16][128]
    uint4*     bfrags2 = (uint4*)((char*)d_ws + 525312);              //  524288 B
    _Float16*  xwG     = (_Float16*)((char*)d_ws + 1049600);          //    8192 B
    _Float16*  feats   = (_Float16*)((char*)d_ws + 1057792);          // 1048576 B
    float*     qw      = (float*)((char*)d_ws + 2106368);             //    3120 B

    // replay-safe: zero flags + hx parity-0 (h_0 = 0) before the LSTM each call
    hipMemsetAsync(d_ws, 0, 1024 + 262144, stream);

    hipLaunchKernelGGL(concat_qw, dim3(1), dim3(256), 0, stream,
                       fm_w, fm_b, c1_w, c1_b, p1_w, p1_b, c2_w, c2_b,
                       p2_w, p2_b, c3_w, c3_b, qw);
    hipLaunchKernelGGL(pack_bfrag2, dim3(128), dim3(256), 0, stream,
                       f_w, i_w, u_w, o_w, bfrags2);
    hipLaunchKernelGGL(pack_xw, dim3(16), dim3(256), 0, stream,
                       f_w, i_w, u_w, o_w, xwG);
    hipLaunchKernelGGL(qcnn_kernel, dim3(512), dim3(256), 0, stream,
                       inputs, qw, feats);
    hipLaunchKernelGGL(lstm_kernel, dim3(256), dim3(256), 0, stream,
                       bfrags2, xwG, feats,
                       f_b, i_b, u_b, o_b, head_w, head_b,
                       flags, hx, (float*)d_out);
}